// Round 9
// baseline (370.578 us; speedup 1.0000x reference)
//
#include <hip/hip_runtime.h>
#include <hip/hip_bf16.h>

// RNN: B=1024, T=512, E=64, H=128, OUT=2, VOCAB=4411
// R9: SINGLE fused kernel (no pe table, no 2nd dispatch).
//  Post-mortem R8: (a) per-CU LDS BW is the limiter: h-bytes/step =
//  #waves x 4KB (every wave reads full K=128). 8 waves = 32KB = ~375cyc.
//  -> back to 4 waves x 32j (16KB) with R8's proven micro-opts (2-deep
//  split-K chains, C-operand seeding, single-register pipelines).
//  (b) the ~78us bench-vs-rocprof gap appears only in 2-kernel graphs
//  (R1/R2 single kernel: gap ~0) -> fuse the input projection in-kernel:
//  x_proj^T[j][b] = sum_e W_ih[j][e] emb[tok_b][e] as 4 MFMAs/step
//  (A = static W_ih bf16 frags, B = 64B/lane emb gather, L2-resident),
//  pipelined 2 steps ahead (load t->cvt+MFMA t+1->consume t+2), seeded
//  with fp32 bias in the C operand.
// Everything proven kept: lgkm-only barrier (globals never drained),
// B-frag-order h in LDS (conflict-free), token LDS staging + register
// token pipeline, rcp-based tanh.
// MFMA 16x16x32_bf16 (m89/m91): A[m][k]: m=L&15,k=(L>>4)*8+s; B[k][n]:
// n=L&15,k=(L>>4)*8+s; D[m][n]: n=L&15,m=(L>>4)*4+reg.

constexpr int Bc    = 1024;
constexpr int Tc    = 512;
constexpr int Ec    = 64;
constexpr int Hc    = 128;
constexpr int OUTc  = 2;

typedef short  short8  __attribute__((ext_vector_type(8)));
typedef float  floatx4 __attribute__((ext_vector_type(4)));

__device__ __forceinline__ unsigned short f2bf(float x) {
    union { __hip_bfloat16 h; unsigned short u; } v;
    v.h = __float2bfloat16(x);
    return v.u;
}
__device__ __forceinline__ float bf2f(unsigned short u) {
    union { float f; unsigned int u; } c;
    c.u = ((unsigned int)u) << 16;
    return c.f;
}
__device__ __forceinline__ unsigned int pack2bf(float lo, float hi) {
    union { __hip_bfloat162 h; unsigned int u; } c;
    c.h = __float22bfloat162_rn(float2{lo, hi});   // lo -> low 16 bits
    return c.u;
}
// 8 fp32 -> short8 bf16 (rne), packed converts.
__device__ __forceinline__ short8 cvt8bf(float4 a, float4 b) {
    union { short8 s; unsigned int u[4]; } r;
    r.u[0] = pack2bf(a.x, a.y);
    r.u[1] = pack2bf(a.z, a.w);
    r.u[2] = pack2bf(b.x, b.y);
    r.u[3] = pack2bf(b.z, b.w);
    return r.s;
}
// tanh(z) = 1 - 2*rcp(exp2(k*z)+1); division-free, exact at saturation.
__device__ __forceinline__ float fast_tanh(float z) {
    const float e = __builtin_amdgcn_exp2f(2.8853900817779268f * z);
    return 1.0f - 2.0f * __builtin_amdgcn_rcpf(e + 1.0f);
}

// Workgroup barrier draining ONLY lgkmcnt (LDS); global loads stay in flight.
#define LGKM_BARRIER() asm volatile("s_waitcnt lgkmcnt(0)\n\ts_barrier" ::: "memory")

constexpr int HT_BUF     = 2048;  // ushorts per h buffer (4 k-tiles x 512)
constexpr int TOK_STRIDE = 513;   // ints per b-row

__global__ __launch_bounds__(256, 1) void rnn_fused(
    const int*   __restrict__ inputs,  // [B, T]
    const float* __restrict__ emb,     // [VOCAB, E]
    const float* __restrict__ W_ih,    // [H, E]
    const float* __restrict__ W_hh,    // [H, H]
    const float* __restrict__ b_ih,    // [H]
    const float* __restrict__ b_hh,    // [H]
    const float* __restrict__ W_lin,   // [OUT, H]
    const float* __restrict__ b_lin,   // [OUT]
    float* __restrict__ out)           // [B, OUT]
{
    const int tid = threadIdx.x;
    const int w   = tid >> 6;      // wave 0..3 -> j in [32w, 32w+32)
    const int L   = tid & 63;
    const int q   = L >> 4;        // 0..3
    const int b   = L & 15;        // batch sub-row / MFMA col n
    const int blk = blockIdx.x;
    const int jb  = w * 32;

    __shared__ __align__(16) unsigned short HT[2 * HT_BUF];
    __shared__ int toks[16 * TOK_STRIDE];

    // Stage 16 token rows (32 KB) into LDS, coalesced.
    {
        const int base = blk * 16 * Tc;
        for (int i = tid; i < 16 * Tc / 4; i += 256) {
            const int4 v4 = *(const int4*)(inputs + base + i * 4);
            const int bb = (i * 4) >> 9, t0 = (i * 4) & 511;
            int* dst = &toks[bb * TOK_STRIDE + t0];
            dst[0] = v4.x; dst[1] = v4.y; dst[2] = v4.z; dst[3] = v4.w;
        }
    }
    // Zero h buffer 0 (h_0 = 0).
    {
        unsigned int* z = (unsigned int*)HT;
        for (int i = tid; i < HT_BUF / 2; i += 256) z[i] = 0u;
    }

    // ---- Static A fragments ----
    // W_hh rows [jb, jb+32): 2 jt x 4 kt frags (32 VGPR).
    short8 wfrag[2][4];
#pragma unroll
    for (int jt = 0; jt < 2; ++jt) {
        const float* wr = W_hh + (jb + jt * 16 + b) * Hc;   // A row m = L&15
#pragma unroll
        for (int kt = 0; kt < 4; ++kt)
            wfrag[jt][kt] = cvt8bf(*(const float4*)(wr + kt * 32 + q * 8),
                                   *(const float4*)(wr + kt * 32 + q * 8 + 4));
    }
    // W_ih rows [jb, jb+32): 2 jt x 2 et frags (16 VGPR).
    short8 ifrag[2][2];
#pragma unroll
    for (int jt = 0; jt < 2; ++jt) {
        const float* wr = W_ih + (jb + jt * 16 + b) * Ec;
#pragma unroll
        for (int et = 0; et < 2; ++et)
            ifrag[jt][et] = cvt8bf(*(const float4*)(wr + et * 32 + q * 8),
                                   *(const float4*)(wr + et * 32 + q * 8 + 4));
    }
    // bias (fp32, seeds the C operand): D rows m = q*4 + r.
    float4 biasv[2];
#pragma unroll
    for (int jt = 0; jt < 2; ++jt) {
        const int j0 = jb + jt * 16 + q * 4;
        const float4 bi = *(const float4*)(b_ih + j0);
        const float4 bh = *(const float4*)(b_hh + j0);
        biasv[jt] = float4{bi.x + bh.x, bi.y + bh.y, bi.z + bh.z, bi.w + bh.w};
    }
#pragma unroll
    for (int jt = 0; jt < 2; ++jt)
        asm volatile("" : "+v"(wfrag[jt][0]), "+v"(wfrag[jt][1]),
                          "+v"(wfrag[jt][2]), "+v"(wfrag[jt][3]),
                          "+v"(ifrag[jt][0]), "+v"(ifrag[jt][1]));

    unsigned short* const ht0 = HT;
    unsigned short* const ht1 = HT + HT_BUF;
    const int rd_base = L * 8;          // + kt*512: lane-sequential, 0 conflicts
    int wr_off[2];
#pragma unroll
    for (int jt = 0; jt < 2; ++jt) {    // j0 = jb+jt*16+q*4 in B-frag order
        const int j0 = jb + jt * 16 + q * 4;
        wr_off[jt] = ((j0 >> 5) << 9) + (((j0 >> 3) & 3) * 16 + b) * 8 + (j0 & 7);
    }

    const int* tr = &toks[b * TOK_STRIDE];
    // emb element base for this lane's B-frag slots: e = et*32 + q*8 + s.
    const int e0 = q * 8;
    const floatx4 zac = (floatx4){0.f, 0.f, 0.f, 0.f};

    __syncthreads();   // tokens + zeroed h0 visible (one-time full drain)

    // ---- Prologue ----
    // xz_cur (t=0): load emb(tok0), cvt, 4 MFMAs seeded with bias.
    // eload: emb(tok1) left in registers (consumed in step 0 for xz of t=1).
    floatx4 xz_cur[2];
    float4  eload[4];
    int     tk;
    {
        const int t0 = tr[0], t1 = tr[1];
        tk = tr[2];
        const float* er0 = emb + (long)t0 * Ec;
        float4 ea = *(const float4*)(er0 + e0);
        float4 eb = *(const float4*)(er0 + e0 + 4);
        float4 ec = *(const float4*)(er0 + 32 + e0);
        float4 ed = *(const float4*)(er0 + 32 + e0 + 4);
        const short8 f0 = cvt8bf(ea, eb);
        const short8 f1 = cvt8bf(ec, ed);
#pragma unroll
        for (int jt = 0; jt < 2; ++jt) {
            floatx4 a = (floatx4){biasv[jt].x, biasv[jt].y, biasv[jt].z, biasv[jt].w};
            a = __builtin_amdgcn_mfma_f32_16x16x32_bf16(ifrag[jt][0], f0, a, 0, 0, 0);
            a = __builtin_amdgcn_mfma_f32_16x16x32_bf16(ifrag[jt][1], f1, a, 0, 0, 0);
            xz_cur[jt] = a;
        }
        const float* er1 = emb + (long)t1 * Ec;
        eload[0] = *(const float4*)(er1 + e0);
        eload[1] = *(const float4*)(er1 + e0 + 4);
        eload[2] = *(const float4*)(er1 + 32 + e0);
        eload[3] = *(const float4*)(er1 + 32 + e0 + 4);
    }

    for (int t = 0; t < Tc; ++t) {
        unsigned short* const rbuf = (t & 1) ? ht1 : ht0;
        unsigned short* const wbuf = (t & 1) ? ht0 : ht1;

        // B fragments: h bf16, lane-sequential (conflict-free).
        short8 bfrag[4];
#pragma unroll
        for (int kt = 0; kt < 4; ++kt)
            bfrag[kt] = *(const short8*)(rbuf + kt * 512 + rd_base);

        // Issue emb loads for t+2 (stay in flight across the lgkm barrier).
        const int tknew = tr[(t + 3 < Tc) ? (t + 3) : (Tc - 1)];
        float4 enew[4];
        {
            const float* er = emb + (long)tk * Ec;
            enew[0] = *(const float4*)(er + e0);
            enew[1] = *(const float4*)(er + e0 + 4);
            enew[2] = *(const float4*)(er + 32 + e0);
            enew[3] = *(const float4*)(er + 32 + e0 + 4);
        }

        // Consume eload (emb of t+1): cvt + 4 MFMAs -> xz_next (off-path).
        floatx4 xz_next[2];
        {
            const short8 f0 = cvt8bf(eload[0], eload[1]);
            const short8 f1 = cvt8bf(eload[2], eload[3]);
#pragma unroll
            for (int jt = 0; jt < 2; ++jt) {
                floatx4 a = (floatx4){biasv[jt].x, biasv[jt].y, biasv[jt].z, biasv[jt].w};
                a = __builtin_amdgcn_mfma_f32_16x16x32_bf16(ifrag[jt][0], f0, a, 0, 0, 0);
                a = __builtin_amdgcn_mfma_f32_16x16x32_bf16(ifrag[jt][1], f1, a, 0, 0, 0);
                xz_next[jt] = a;
            }
        }

        // W_hh: per jt two independent 2-deep chains, C-seeded.
#pragma unroll
        for (int jt = 0; jt < 2; ++jt) {
            floatx4 a0 = __builtin_amdgcn_mfma_f32_16x16x32_bf16(
                wfrag[jt][0], bfrag[0], xz_cur[jt], 0, 0, 0);
            floatx4 a1 = __builtin_amdgcn_mfma_f32_16x16x32_bf16(
                wfrag[jt][2], bfrag[2], zac, 0, 0, 0);
            a0 = __builtin_amdgcn_mfma_f32_16x16x32_bf16(
                wfrag[jt][1], bfrag[1], a0, 0, 0, 0);
            a1 = __builtin_amdgcn_mfma_f32_16x16x32_bf16(
                wfrag[jt][3], bfrag[3], a1, 0, 0, 0);

            const float h0 = fast_tanh(a0[0] + a1[0]);
            const float h1 = fast_tanh(a0[1] + a1[1]);
            const float h2 = fast_tanh(a0[2] + a1[2]);
            const float h3 = fast_tanh(a0[3] + a1[3]);
            uint2 pk;
            pk.x = pack2bf(h0, h1);
            pk.y = pack2bf(h2, h3);
            *(uint2*)(wbuf + wr_off[jt]) = pk;
        }

        LGKM_BARRIER();   // drains LDS only; emb prefetch stays outstanding

        xz_cur[0] = xz_next[0]; xz_cur[1] = xz_next[1];
        eload[0] = enew[0]; eload[1] = enew[1];
        eload[2] = enew[2]; eload[3] = enew[3];
        tk = tknew;
    }

    // Final h is in ht0 (t=511 wrote ht0), B-fragment order. Linear head.
    if (tid < 16 * OUTc) {
        const int bb = tid >> 1, o = tid & 1;
        float s = b_lin[o];
        const float* wl = W_lin + o * Hc;
#pragma unroll 8
        for (int k = 0; k < Hc; ++k) {
            const int off = ((k >> 5) << 9) + (((k >> 3) & 3) * 16 + bb) * 8 + (k & 7);
            s = fmaf(bf2f(ht0[off]), wl[k], s);
        }
        out[(blk * 16 + bb) * OUTc + o] = s;
    }
}

extern "C" void kernel_launch(void* const* d_in, const int* in_sizes, int n_in,
                              void* d_out, int out_size, void* d_ws, size_t ws_size,
                              hipStream_t stream) {
    const int*   inputs    = (const int*)d_in[0];
    const float* emb_table = (const float*)d_in[1];
    const float* W_ih      = (const float*)d_in[2];
    const float* W_hh      = (const float*)d_in[3];
    const float* b_ih      = (const float*)d_in[4];
    const float* b_hh      = (const float*)d_in[5];
    const float* W_lin     = (const float*)d_in[6];
    const float* b_lin     = (const float*)d_in[7];
    float* out = (float*)d_out;

    rnn_fused<<<Bc / 16, 256, 0, stream>>>(inputs, emb_table, W_ih, W_hh,
                                           b_ih, b_hh, W_lin, b_lin, out);
}

// Round 10
// 239.359 us; speedup vs baseline: 1.5482x; 1.5482x over previous
//
#include <hip/hip_runtime.h>
#include <hip/hip_bf16.h>

// RNN: B=1024, T=512, E=64, H=128, OUT=2, VOCAB=4411
// R10 = R8's rnn_mfma BYTE-IDENTICAL (167.5us verified; R6/R9 showed any
// structural perturbation of the K-loop regresses) + faster pe_kernel.
//  R9 post-mortem: in-kernel emb fusion collapsed (VGPR=76 -> compiler sank
//  the emb prefetch, exposing L2 latency every step; kernel 311us). Also:
//  the ~59us bench-vs-rocprof gap persists with a SINGLE kernel -> it is
//  fixed harness overhead, not the 2nd dispatch. So the two-kernel split
//  stands; pe_kernel (~19us: 4411 tiny blocks) is the recoverable term.
//  New pe: 276 blocks x 256 thr, 16 vocab rows staged in 4KB LDS, thread =
//  (vocab-half, j); W_ih row in regs; coalesced stores. Predict ~6-10us.
// rnn_mfma: 8 waves x 16j, lgkm-only barrier, B-frag-order h (conflict-free),
// split-K 2-deep MFMA chains C-seeded, token LDS staging + register token,
// depth-2 xp pipeline, rcp-tanh.

constexpr int Bc    = 1024;
constexpr int Tc    = 512;
constexpr int Ec    = 64;
constexpr int Hc    = 128;
constexpr int OUTc  = 2;
constexpr int VOCAB = 4411;

typedef short  short8  __attribute__((ext_vector_type(8)));
typedef float  floatx4 __attribute__((ext_vector_type(4)));

__device__ __forceinline__ unsigned short f2bf(float x) {
    union { __hip_bfloat16 h; unsigned short u; } v;
    v.h = __float2bfloat16(x);
    return v.u;
}
__device__ __forceinline__ float bf2f(unsigned short u) {
    union { float f; unsigned int u; } c;
    c.u = ((unsigned int)u) << 16;
    return c.f;
}
__device__ __forceinline__ unsigned int pack2bf(float lo, float hi) {
    union { __hip_bfloat162 h; unsigned int u; } c;
    c.h = __float22bfloat162_rn(float2{lo, hi});   // lo -> low 16 bits
    return c.u;
}
// tanh(z) = 1 - 2*rcp(exp2(k*z)+1); division-free, exact at saturation.
__device__ __forceinline__ float fast_tanh(float z) {
    const float e = __builtin_amdgcn_exp2f(2.8853900817779268f * z);
    return 1.0f - 2.0f * __builtin_amdgcn_rcpf(e + 1.0f);
}

// Workgroup barrier draining ONLY lgkmcnt (LDS); global loads stay in flight.
#define LGKM_BARRIER() asm volatile("s_waitcnt lgkmcnt(0)\n\ts_barrier" ::: "memory")

// ---------------- Kernel 1: pe[v][j] = emb[v].W_ih[j] + b_ih[j] + b_hh[j] ----
// 256 threads: half = tid>>7 (vocab split), j = tid&127. 16 vocab rows/block
// staged in LDS; each thread does 8 rows x 64 FMA (broadcast LDS reads).
constexpr int PV = 16;
__global__ __launch_bounds__(256) void pe_kernel(
    const float* __restrict__ emb, const float* __restrict__ W_ih,
    const float* __restrict__ b_ih, const float* __restrict__ b_hh,
    float* __restrict__ pe)
{
    const int tid  = threadIdx.x;
    const int j    = tid & 127;
    const int half = tid >> 7;          // 0/1: which 8 vocab rows
    const int v0   = blockIdx.x * PV;

    __shared__ float es[PV * Ec];       // 4 KB
    for (int i = tid; i < PV * Ec / 4; i += 256) {
        const int flat = i * 4, vv = flat >> 6;
        if (v0 + vv < VOCAB)
            *(float4*)&es[flat] = *(const float4*)(emb + (long)(v0 + vv) * Ec + (flat & 63));
    }

    float4 wr[Ec / 4];
#pragma unroll
    for (int e = 0; e < Ec / 4; ++e)
        wr[e] = *(const float4*)(W_ih + j * Ec + e * 4);
    const float bias = b_ih[j] + b_hh[j];

    __syncthreads();

    const int vbeg = half * (PV / 2), vend = vbeg + PV / 2;
    for (int vv = vbeg; vv < vend; ++vv) {
        if (v0 + vv >= VOCAB) break;
        const float* er = &es[vv * Ec];
        float a0 = bias, a1 = 0.f, a2 = 0.f, a3 = 0.f;
#pragma unroll
        for (int e = 0; e < Ec / 4; ++e) {
            const float4 E = *(const float4*)(er + 4 * e);   // LDS broadcast
            a0 = fmaf(E.x, wr[e].x, a0);
            a1 = fmaf(E.y, wr[e].y, a1);
            a2 = fmaf(E.z, wr[e].z, a2);
            a3 = fmaf(E.w, wr[e].w, a3);
        }
        pe[(long)(v0 + vv) * Hc + j] = (a0 + a1) + (a2 + a3);
    }
}

// ---------------- Kernel 2: MFMA recurrence (R8, byte-identical) ----------------
constexpr int HT_BUF     = 2048;  // ushorts per h buffer (4 k-tiles x 512)
constexpr int TOK_STRIDE = 513;   // ints per b-row

__global__ __attribute__((amdgpu_flat_work_group_size(512, 512)))
void rnn_mfma(
    const int*   __restrict__ inputs,  // [B, T]
    const float* __restrict__ pe,      // [VOCAB, H]
    const float* __restrict__ W_hh,    // [H, H]
    const float* __restrict__ W_lin,   // [OUT, H]
    const float* __restrict__ b_lin,   // [OUT]
    float* __restrict__ out)           // [B, OUT]
{
    const int tid = threadIdx.x;
    const int w   = tid >> 6;      // wave 0..7 -> j in [16w, 16w+16)
    const int L   = tid & 63;
    const int q   = L >> 4;        // 0..3
    const int b   = L & 15;        // batch sub-row / MFMA col
    const int blk = blockIdx.x;
    const int jb  = w * 16;

    __shared__ __align__(16) unsigned short HT[2 * HT_BUF];
    __shared__ int toks[16 * TOK_STRIDE];

    // Stage 16 token rows (32 KB) into LDS, coalesced.
    {
        const int base = blk * 16 * Tc;
        for (int i = tid; i < 16 * Tc / 4; i += 512) {
            const int4 v4 = *(const int4*)(inputs + base + i * 4);
            const int bb = (i * 4) >> 9, t0 = (i * 4) & 511;
            int* dst = &toks[bb * TOK_STRIDE + t0];
            dst[0] = v4.x; dst[1] = v4.y; dst[2] = v4.z; dst[3] = v4.w;
        }
    }
    // Zero h buffer 0 (h_0 = 0): 1024 dwords = all of ht0.
    {
        unsigned int* z = (unsigned int*)HT;
        for (int i = tid; i < HT_BUF / 2; i += 512) z[i] = 0u;
    }

    // Static A fragments: W_hh rows [jb, jb+16) as bf16 (4 frags, 16 VGPR).
    short8 wfrag[4];
    {
        const float* wr = W_hh + (jb + b) * Hc;             // A row m = L&15
#pragma unroll
        for (int kt = 0; kt < 4; ++kt) {
            const float4 w0 = *(const float4*)(wr + kt * 32 + q * 8);
            const float4 w1 = *(const float4*)(wr + kt * 32 + q * 8 + 4);
            union { short8 s; unsigned short u[8]; } uf;
            uf.u[0] = f2bf(w0.x); uf.u[1] = f2bf(w0.y);
            uf.u[2] = f2bf(w0.z); uf.u[3] = f2bf(w0.w);
            uf.u[4] = f2bf(w1.x); uf.u[5] = f2bf(w1.y);
            uf.u[6] = f2bf(w1.z); uf.u[7] = f2bf(w1.w);
            wfrag[kt] = uf.s;
        }
    }
    asm volatile("" : "+v"(wfrag[0]), "+v"(wfrag[1]),
                      "+v"(wfrag[2]), "+v"(wfrag[3]));

    unsigned short* const ht0 = HT;
    unsigned short* const ht1 = HT + HT_BUF;
    const int rd_base = L * 8;          // + kt*512: lane-sequential, 0 conflicts
    // Write offset: lane owns z[j0..j0+3][b], j0 = jb + q*4, B-frag order.
    const int j0     = jb + q * 4;
    const int wr_off = ((j0 >> 5) << 9) + (((j0 >> 3) & 3) * 16 + b) * 8 + (j0 & 7);
    const int xp_off = jb + q * 4;      // pe column base for this lane

    const int* tr = &toks[b * TOK_STRIDE];
    const floatx4 zac = (floatx4){0.f, 0.f, 0.f, 0.f};

    __syncthreads();   // tokens + zeroed h0 visible (one-time full drain)

    // Prologue: xp for t=0 and t=1.
    float4 xpc, xpn;
    {
        const int t0 = tr[0], t1 = tr[1];
        xpc = *(const float4*)(pe + (long)t0 * Hc + xp_off);
        xpn = *(const float4*)(pe + (long)t1 * Hc + xp_off);
    }

    for (int t = 0; t < Tc; ++t) {
        unsigned short* const rbuf = (t & 1) ? ht1 : ht0;
        unsigned short* const wbuf = (t & 1) ? ht0 : ht1;

        // B fragments: h bf16, lane-sequential (conflict-free by construction).
        short8 bfrag[4];
#pragma unroll
        for (int kt = 0; kt < 4; ++kt)
            bfrag[kt] = *(const short8*)(rbuf + kt * 512 + rd_base);

        // Prefetch pe row for t+2 (stays in flight across the lgkm barrier).
        float4 xp2;
        {
            const int tk = tr[(t + 2 < Tc) ? (t + 2) : (Tc - 1)];
            xp2 = *(const float4*)(pe + (long)tk * Hc + xp_off);
        }

        // Split-K: two independent 2-deep MFMA chains, C-operand seeded.
        floatx4 acc0 = (floatx4){xpc.x, xpc.y, xpc.z, xpc.w};
        acc0 = __builtin_amdgcn_mfma_f32_16x16x32_bf16(wfrag[0], bfrag[0], acc0, 0, 0, 0);
        floatx4 acc1 = __builtin_amdgcn_mfma_f32_16x16x32_bf16(wfrag[2], bfrag[2], zac, 0, 0, 0);
        acc0 = __builtin_amdgcn_mfma_f32_16x16x32_bf16(wfrag[1], bfrag[1], acc0, 0, 0, 0);
        acc1 = __builtin_amdgcn_mfma_f32_16x16x32_bf16(wfrag[3], bfrag[3], acc1, 0, 0, 0);

        // z = acc0 + acc1 -> tanh -> bf16 -> one b64 LDS write.
        const float h0 = fast_tanh(acc0[0] + acc1[0]);
        const float h1 = fast_tanh(acc0[1] + acc1[1]);
        const float h2 = fast_tanh(acc0[2] + acc1[2]);
        const float h3 = fast_tanh(acc0[3] + acc1[3]);
        uint2 pk;
        pk.x = pack2bf(h0, h1);
        pk.y = pack2bf(h2, h3);
        *(uint2*)(wbuf + wr_off) = pk;

        LGKM_BARRIER();   // drains LDS only; pe prefetch stays outstanding

        xpc = xpn;
        xpn = xp2;
    }

    // Final h is in ht0 (t=511 wrote ht0), B-fragment order. Linear head.
    if (tid < 16 * OUTc) {
        const int bb = tid >> 1, o = tid & 1;
        float s = b_lin[o];
        const float* wl = W_lin + o * Hc;
#pragma unroll 8
        for (int k = 0; k < Hc; ++k) {
            const int off = ((k >> 5) << 9) + (((k >> 3) & 3) * 16 + bb) * 8 + (k & 7);
            s = fmaf(bf2f(ht0[off]), wl[k], s);
        }
        out[(blk * 16 + bb) * OUTc + o] = s;
    }
}

extern "C" void kernel_launch(void* const* d_in, const int* in_sizes, int n_in,
                              void* d_out, int out_size, void* d_ws, size_t ws_size,
                              hipStream_t stream) {
    const int*   inputs    = (const int*)d_in[0];
    const float* emb_table = (const float*)d_in[1];
    const float* W_ih      = (const float*)d_in[2];
    const float* W_hh      = (const float*)d_in[3];
    const float* b_ih      = (const float*)d_in[4];
    const float* b_hh      = (const float*)d_in[5];
    const float* W_lin     = (const float*)d_in[6];
    const float* b_lin     = (const float*)d_in[7];
    float* out = (float*)d_out;

    float* pe = (float*)d_ws;  // VOCAB*H*4 = 2.26 MB
    pe_kernel<<<(VOCAB + PV - 1) / PV, 256, 0, stream>>>(emb_table, W_ih, b_ih, b_hh, pe);
    rnn_mfma<<<Bc / 16, 512, 0, stream>>>(inputs, pe, W_hh, W_lin, b_lin, out);
}